// Round 13
// baseline (167.063 us; speedup 1.0000x reference)
//
#include <hip/hip_runtime.h>
#include <math.h>

#define M_LEN 40000
#define B_SZ 16
#define K_TAPS 201
#define T_HALF 100
#define L_OUT 39800
#define TL 128               // outputs per block (halved for 3 blocks/CU)
#define NTILES 311           // ceil(L_OUT / TL)
#define NPS 330              // staged series positions (TL + 202)
#define NPX 332              // x positions staged
#define XSTR 336             // x f16 stride
#define SSTR 176             // series row stride in dwords (352 f16; reads reach 174)
#define NSER 20
#define KT 7                 // k-tiles: 7*32 = 224 >= 203 used taps
#define CBH 72               // CB2 slot stride in dwords; 72 % 32 = 8 -> write banks
                             // {8ci+2gq} distinct (16 lanes), zero write conflicts
#define NSLOT 68
#define NTHR 512

typedef unsigned int uint;
typedef unsigned short ushort_;
typedef __fp16 h2 __attribute__((ext_vector_type(2)));
typedef __fp16 h8 __attribute__((ext_vector_type(8)));
typedef float f4 __attribute__((ext_vector_type(4)));

static __device__ __forceinline__ float half_of(uint u, int hi) {
    ushort_ us = hi ? (ushort_)(u >> 16) : (ushort_)(u & 0xffffu);
    _Float16 h; __builtin_memcpy(&h, &us, 2); return (float)h;
}
static __device__ __forceinline__ uint pk2(float a, float b) {
    h2 h = __builtin_amdgcn_cvt_pkrtz(a, b);
    uint r; __builtin_memcpy(&r, &h, 4); return r;
}
static __device__ __forceinline__ h8 mk8(uint a, uint b, uint c, uint d) {
    uint uu[4] = {a, b, c, d}; h8 h; __builtin_memcpy(&h, uu, 16); return h;
}

// ---------------- prep kernel: B weight panel [16 cols][224 taps] f16 --------
// col 0: wx; col 1: wc; cols 2+4sg+{0,1,2,3}: wPr,wPi,wNr,wNi for sg; 10-15: 0
__global__ void prep_weights(const float* __restrict__ wx, const float* __restrict__ wc,
                             const float* __restrict__ wr, const float* __restrict__ wi,
                             _Float16* __restrict__ Wb) {
    int idx = blockIdx.x * 256 + threadIdx.x;
    if (idx >= 16 * 224) return;
    int n = idx / 224, t = idx % 224;
    float f = 0.f;
    if (n == 0)      f = (t <= 200) ? wx[t] : 0.f;
    else if (n == 1) f = (t <= 200) ? wc[t] : 0.f;
    else if (n < 10) {
        int q = n - 2, sg = q >> 2, c = q & 3;
        if (c < 2) {                       // wPr / wPi
            f = (t <= 200) ? ((c == 1) ? wi : wr)[(2 + sg) * K_TAPS + t] : 0.f;
        } else {                           // wNr / wNi (shifted taps)
            int tt = t - (sg + 1);
            f = (tt >= 0 && tt <= 200) ? ((c == 3) ? wi : wr)[(1 - sg) * K_TAPS + tt] : 0.f;
        }
    }
    Wb[idx] = (_Float16)f;
}

// ---------------- series construction (identical math to verified R0-R12) ----
static __device__ __forceinline__ void calc_series(
        const _Float16 (*sxr)[XSTR], const _Float16 (*sxi)[XSTR], int pos, float* v) {
    const int ix = pos + 2;
    float x0r = (float)sxr[0][ix], x0i = (float)sxi[0][ix];
    float x1r = (float)sxr[1][ix], x1i = (float)sxi[1][ix];
    float p0 = x0r * x0r + x0i * x0i;
    float p1 = x1r * x1r + x1i * x1i;
    v[0] = 2.f * p0 + p1;
    v[1] = 2.f * p1 + p0;
    v[2] = x0r * x1r + x0i * x1i;       // qr
    v[3] = x0i * x1r - x0r * x1i;       // qi
#pragma unroll
    for (int sg = 0; sg < 2; ++sg) {
        const int jx = ix - (sg + 1);
        float a0r = (float)sxr[0][jx], a0i = (float)sxi[0][jx];
        float a1r = (float)sxr[1][jx], a1i = (float)sxi[1][jx];
        float U0r = x0r * a0r + x0i * a0i;
        float U0i = x0i * a0r - x0r * a0i;
        float U1r = x1r * a1r + x1i * a1i;
        float U1i = x1i * a1r - x1r * a1i;
        const int ba = 4 + sg * 8;
        v[ba + 0] = 2.f * U0r + U1r;        // A0r
        v[ba + 1] = 2.f * U1r + U0r;        // A1r
        v[ba + 2] = 2.f * U0i + U1i;        // A0i
        v[ba + 3] = 2.f * U1i + U0i;        // A1i
        v[ba + 4] = x0r * a1r + x0i * a1i;  // Br0
        v[ba + 5] = x1r * a0r + x1i * a0i;  // Br1
        v[ba + 6] = x0i * a1r - x0r * a1i;  // Bi0
        v[ba + 7] = x1i * a0r - x1r * a0i;  // Bi1
    }
}

// R12 structure scaled to TL=128 for occupancy: LDS 79.7K -> 50.4K = 3 blocks/CU
// (24 waves/CU, 6/SIMD vs 4). launch_bounds(512,6) caps regs ~85; F-ring of 8
// (chunk-paired) + Bf 28 + Cc 8 fits. Wave map: rho(2) x sq(4) x 5 series.
__global__ __launch_bounds__(NTHR, 6) void snse_kernel(
    const float* __restrict__ g_xr, const float* __restrict__ g_xi,
    const float* __restrict__ g_ti, const float* __restrict__ g_c00,
    const float* __restrict__ g_wx, const float* __restrict__ g_wc,
    const _Float16* __restrict__ Wb,
    float* __restrict__ g_out)
{
    __shared__ uint SEe[NSER * SSTR];                       // 14080 B
    __shared__ uint SEo[NSER * SSTR];                       // 14080 B (shift-1)
    __shared__ __align__(16) uint CB2[NSLOT * CBH];         // 19584 B
    __shared__ _Float16 s_xr_h[2][XSTR], s_xi_h[2][XSTR];   //  2688 B

    const int tid = threadIdx.x;
    const int b   = blockIdx.y;
    const int l0  = blockIdx.x * TL;

    const float tdb    = g_ti[b * 4 + 0];
    const float P      = expf(tdb * 0.23025850929940457f) * 0.5f;
    const float sP     = sqrtf(P);
    const float inv_sP = 1.0f / sP;
    const float C00    = g_c00[0];

    // ---- stage x (f16, scaled) ----
    for (int idx = tid; idx < 2 * NPX; idx += NTHR) {
        int pidx = idx >> 1, ch = idx & 1;
        int m = l0 - 2 + pidx;
        int mw = m < 0 ? m + M_LEN : (m >= M_LEN ? m - M_LEN : m);
        int gg = (b * M_LEN + mw) * 2 + ch;
        s_xr_h[ch][pidx] = (_Float16)(g_xr[gg] * sP);
        s_xi_h[ch][pidx] = (_Float16)(g_xi[gg] * sP);
    }
    __syncthreads();

    // ---- stage series (packed f16 pairs), zero beyond NPS ----
    for (int p = tid; p < SSTR; p += NTHR) {
        float v0[NSER], v1[NSER];
#pragma unroll
        for (int a = 0; a < NSER; ++a) { v0[a] = 0.f; v1[a] = 0.f; }
        const int m0 = 2 * p, m1 = 2 * p + 1;
        if (m0 < NPS) calc_series(s_xr_h, s_xi_h, m0, v0);
        if (m1 < NPS) calc_series(s_xr_h, s_xi_h, m1, v1);
#pragma unroll
        for (int a = 0; a < NSER; ++a)
            SEe[a * SSTR + p] = pk2(v0[a], v1[a]);
    }
    __syncthreads();

    // ---- shifted copy: SEo[d] = elements (2d+1, 2d+2) ----
    for (int d = tid; d < NSER * SSTR; d += NTHR) {
        int row = d / SSTR, cc = d - row * SSTR;
        uint lo = SEe[d] >> 16;
        uint hi = (cc < SSTR - 1) ? (SEe[d + 1] << 16) : 0u;
        SEo[d] = lo | hi;
    }
    __syncthreads();

    // ---- MFMA conv phase ----
    // wave w: rho = parity (w&1), sq = w>>1 -> series a = 5*sq + as, as 0..4.
    // chunks c=0..3: 16 stride-2 positions at rho+32c; A[m][k]=S[rho+32c+2m+k];
    // lane: m=cn, k = 32kt + 8gq + j; chunk c, k-tile kt -> fragment c+kt.
    // F-ring of 8: pair {0,1} uses frags 0..7; then frags 8,9 -> slots 0,1;
    // pair {2,3} uses frags 2..9 (slots 2..7,0,1).
    {
        const int w    = tid >> 6;
        const int lane = tid & 63;
        const int cn   = lane & 15;   // A row m / B-C col
        const int gq   = lane >> 4;   // k-group / C row-quad
        const int rho  = w & 1, sq = w >> 1;

        h8 Bf[KT];
#pragma unroll
        for (int i = 0; i < KT; ++i) {
            h8 t; __builtin_memcpy(&t, Wb + cn * 224 + 32 * i + 8 * gq, 16);
            Bf[i] = t;
        }

        const uint* SEp = rho ? SEo : SEe;
        const int dw0 = cn + 4 * gq;
        const int ub0 = rho * 32 + 2 * gq;

#pragma unroll 1
        for (int as = 0; as < 5; ++as) {
            const int a = 5 * sq + as;
            const uint* Pa = SEp + a * SSTR + dw0;

            // slot for this lane's column (or -1)
            int slot = -1;
            if (a < 4) {
                if (cn == (a >> 1)) slot = a;
            } else {
                int cb = 2 + 4 * ((a - 4) >> 3);
                int ci = cn - cb;
                if (ci >= 0 && ci < 4) slot = 4 + (a - 4) * 4 + ci;
            }

            h8 F[8];
#pragma unroll
            for (int i = 0; i < 8; ++i)
                F[i] = mk8(Pa[16 * i], Pa[16 * i + 1], Pa[16 * i + 2], Pa[16 * i + 3]);

#pragma unroll
            for (int pr = 0; pr < 2; ++pr) {
                f4 Cc[2] = {};
#pragma unroll
                for (int kt = 0; kt < KT; ++kt) {
#pragma unroll
                    for (int cc = 0; cc < 2; ++cc) {
                        const int c = 2 * pr + cc;
                        Cc[cc] = __builtin_amdgcn_mfma_f32_16x16x32_f16(
                            F[(c + kt) & 7], Bf[kt], Cc[cc], 0, 0, 0);
                    }
                }
                if (pr == 0) {   // frags 8,9 into ring slots 0,1 (frags 0,1 dead)
                    F[0] = mk8(Pa[128], Pa[129], Pa[130], Pa[131]);
                    F[1] = mk8(Pa[144], Pa[145], Pa[146], Pa[147]);
                }
                if (slot >= 0) {
#pragma unroll
                    for (int cc = 0; cc < 2; ++cc) {
                        const int c = 2 * pr + cc;
                        uint2 v;
                        v.x = pk2(Cc[cc][0], Cc[cc][1]);
                        v.y = pk2(Cc[cc][2], Cc[cc][3]);
                        *(uint2*)&CB2[slot * CBH + ub0 + 8 * c] = v;
                    }
                }
            }
        }
    }
    __syncthreads();

    // ---- epilogue: one (pos, nn) unit per thread (tid < 256) ----
    if (tid < 2 * TL) {
        const int pos = tid >> 1, nn = tid & 1;
        const int l = l0 + pos;

        const float wx100 = (float)(_Float16)g_wx[T_HALF];
        const float wc100 = (float)(_Float16)g_wc[T_HALF];

        // CB2 read: dword = (pos&1)*32 + (pos>>2), half = (pos>>1)&1
        // (R12's proven parity-plane formula with plane size halved 64->32)
        const int cbb = (pos & 1) * 32 + (pos >> 2);
        const int hl  = (pos >> 1) & 1;

        float acc_ix = half_of(CB2[nn * CBH + cbb], hl);
        float acc_qr = half_of(CB2[2 * CBH + cbb], hl);
        float acc_qi = half_of(CB2[3 * CBH + cbb], hl);

        const int pc = pos + T_HALF;
        acc_ix = fmaf(-wx100, half_of(SEe[nn * SSTR + (pc >> 1)], pc & 1), acc_ix);
        acc_qr = fmaf(-wc100, half_of(SEe[2 * SSTR + (pc >> 1)], pc & 1), acc_qr);
        acc_qi = fmaf(-wc100, half_of(SEe[3 * SSTR + (pc >> 1)], pc & 1), acc_qi);

        float fAr[4], fAi[4], fBr[4], fBi[4];
#pragma unroll
        for (int sg = 0; sg < 2; ++sg) {
            const int sip = 2 + sg, sin_ = 1 - sg;
            const int sb = 4 + 32 * sg;
#define SRD(si, ci) half_of(CB2[(sb + 4 * (si) + (ci)) * CBH + cbb], hl)
            fAr[sip]  = SRD(nn, 0)     - SRD(2 + nn, 1);
            fAi[sip]  = SRD(nn, 1)     + SRD(2 + nn, 0);
            fAr[sin_] = SRD(nn, 2)     + SRD(2 + nn, 3);
            fAi[sin_] = SRD(nn, 3)     - SRD(2 + nn, 2);
            fBr[sip]  = SRD(4 + nn, 0) - SRD(6 + nn, 1);
            fBi[sip]  = SRD(4 + nn, 1) + SRD(6 + nn, 0);
            fBr[sin_] = SRD(5 - nn, 2) + SRD(7 - nn, 3);
            fBi[sin_] = SRD(5 - nn, 3) - SRD(7 - nn, 2);
#undef SRD
        }

        const int xc = pos + T_HALF + 2;
        float X0r = (float)s_xr_h[0][xc], X0i = (float)s_xi_h[0][xc];
        float X1r = (float)s_xr_h[1][xc], X1i = (float)s_xi_h[1][xc];
        float pw  = X0r * X0r + X0i * X0i + X1r * X1r + X1i * X1i;
        float phi = C00 * pw + 2.f * acc_ix;
        float sph, cph;
        __sincosf(phi, &sph, &cph);
        float qcr = acc_qr;
        float qci = nn ? -acc_qi : acc_qi;
        float br_ = nn ? X1r : X0r, bi_ = nn ? X1i : X0i;
        float or_ = nn ? X0r : X1r, oi_ = nn ? X0i : X1i;
        float ici_r = -(or_ * qci + oi_ * qcr);
        float ici_i =   or_ * qcr - oi_ * qci;
        float fw_r = 0.f, fw_i = 0.f;
        const int ssf[4] = {-2, -1, 1, 2};
#pragma unroll
        for (int si = 0; si < 4; ++si) {
            int sx = xc - ssf[si];
            float xnr  = (float)s_xr_h[nn][sx],     xni = (float)s_xi_h[nn][sx];
            float xor_ = (float)s_xr_h[1 - nn][sx], xoi = (float)s_xi_h[1 - nn][sx];
            fw_r += xnr * fAr[si] - xni * fAi[si]
                  + xor_ * fBr[si] - xoi * fBi[si];
            fw_i += xnr * fAi[si] + xni * fAr[si]
                  + xor_ * fBi[si] + xoi * fBr[si];
        }
        float out_r = br_ * cph - bi_ * sph + ici_r + fw_r;
        float out_i = br_ * sph + bi_ * cph + ici_i + fw_i;
        if (l < L_OUT) {
            int oidx = (((b * L_OUT) + l) * 2 + nn) * 2;
            g_out[oidx]     = out_r * inv_sP;
            g_out[oidx + 1] = out_i * inv_sP;
        }
    }
}

extern "C" void kernel_launch(void* const* d_in, const int* in_sizes, int n_in,
                              void* d_out, int out_size, void* d_ws, size_t ws_size,
                              hipStream_t stream) {
    const float* xr  = (const float*)d_in[0];
    const float* xi  = (const float*)d_in[1];
    const float* ti  = (const float*)d_in[2];
    const float* c00 = (const float*)d_in[3];
    const float* wx  = (const float*)d_in[4];
    const float* wc  = (const float*)d_in[5];
    const float* wr  = (const float*)d_in[6];
    const float* wi  = (const float*)d_in[7];
    float* out = (float*)d_out;
    _Float16* Wb = (_Float16*)d_ws;   // 16*224*2 = 7168 bytes

    prep_weights<<<dim3((16 * 224 + 255) / 256), dim3(256), 0, stream>>>(wx, wc, wr, wi, Wb);

    dim3 grid(NTILES, B_SZ, 1);
    dim3 block(NTHR, 1, 1);
    snse_kernel<<<grid, block, 0, stream>>>(xr, xi, ti, c00, wx, wc, Wb, out);
}